// Round 12
// baseline (186.286 us; speedup 1.0000x reference)
//
#include <hip/hip_runtime.h>
#include <hip/hip_bf16.h>
#include <stdint.h>
#include <math.h>

// Problem constants (fixed by the reference)
#define NH   16
#define HDIM 64
#define SEQ  2048
#define DM   1024
#define NB   2
#define MTOK (NB * SEQ)   // 4096

typedef __bf16 bf16x8 __attribute__((ext_vector_type(8)));  // 4 VGPRs, MFMA A/B frag
typedef __bf16 bf16x4 __attribute__((ext_vector_type(4)));  // 2 VGPRs, 16x16x16 frag
typedef short  short4v __attribute__((ext_vector_type(4)));
typedef float  f32x4  __attribute__((ext_vector_type(4)));  // MFMA C/D frag

__device__ __forceinline__ unsigned short f2bf(float f) {
  union { float f; unsigned int u; } c; c.f = f;
  unsigned int u = c.u;
  return (unsigned short)((u + 0x7FFFu + ((u >> 16) & 1u)) >> 16);  // RNE
}
__device__ __forceinline__ float bf2f(unsigned short s) {
  union { unsigned int u; float f; } c; c.u = ((unsigned int)s) << 16;
  return c.f;
}
__device__ __forceinline__ unsigned int pk2bf(float a, float b) {   // packed RNE cvt
  __hip_bfloat162 h = __float22bfloat162_rn(float2{a, b});
  return *reinterpret_cast<unsigned int*>(&h);
}

// raw v_exp_f32 (base-2): OCML exp2f carries edge handling; scores are small fp32,
// exp2(-inf)=0 preserved. R10-proven: VALUBusy 51 -> 38.
__device__ __forceinline__ float fexp2(float x) {
#if __has_builtin(__builtin_amdgcn_exp2f)
  return __builtin_amdgcn_exp2f(x);
#else
  return exp2f(x);
#endif
}

// 16x16x16 bf16 MFMA with builtin-name portability (gfx950 bf16-typed vs legacy _1k)
__device__ __forceinline__ f32x4 mfma16(short4v a, short4v b, f32x4 c) {
#if __has_builtin(__builtin_amdgcn_mfma_f32_16x16x16_bf16)
  return __builtin_amdgcn_mfma_f32_16x16x16_bf16(
      __builtin_bit_cast(bf16x4, a), __builtin_bit_cast(bf16x4, b), c, 0, 0, 0);
#else
  return __builtin_amdgcn_mfma_f32_16x16x16bf16_1k(a, b, c, 0, 0, 0);
#endif
}

// async global->LDS, 16B per lane. LDS dest = wave-uniform base + lane*16 (m104/m108).
__device__ __forceinline__ void async_copy16(const void* g, void* l) {
  __builtin_amdgcn_global_load_lds((__attribute__((address_space(1))) void*)g,
                                   (__attribute__((address_space(3))) void*)l,
                                   16, 0, 0);
}

// ---------------------------------------------------------------- fused casts (1 launch, exact grid)
__global__ void cast_all(const float* __restrict__ x,  const float* __restrict__ wq,
                         const float* __restrict__ wk, const float* __restrict__ wv,
                         const float* __restrict__ wo,
                         unsigned short* __restrict__ xb,
                         unsigned short* __restrict__ wqkvb,
                         unsigned short* __restrict__ wob) {
  const int i = blockIdx.x * 256 + threadIdx.x;
  float4 v;
  uint2* dstp;
  int idx;
  if (i < (1 << 20)) {
    v = reinterpret_cast<const float4*>(x)[i];
    dstp = reinterpret_cast<uint2*>(xb); idx = i;
  } else {
    const int j = i - (1 << 20);
    const int seg = j >> 18;            // 0..3
    idx = j & ((1 << 18) - 1);
    const float* w = (seg == 0) ? wq : (seg == 1) ? wk : (seg == 2) ? wv : wo;
    v = reinterpret_cast<const float4*>(w)[idx];
    if (seg < 3) { dstp = reinterpret_cast<uint2*>(wqkvb); idx += seg * (1 << 18); }
    else         { dstp = reinterpret_cast<uint2*>(wob); }
  }
  uint2 o;
  o.x = pk2bf(v.x, v.y); o.y = pk2bf(v.z, v.w);
  dstp[idx] = o;
}

// ---------------------------------------------------------------- GEMM (NT): C[m,n] = sum_k A[m,k]*B[n,k]
// m97 structure + R12: BK=64 as TWO BK=32 sub-stages per barrier round — halves the
// barrier + vmcnt(0)-drain count (32 -> 16 iters) while keeping each sub-buffer's
// DMA chunk->address mapping and bank profile identical to the proven BK=32 layout.
// MODE 0 (BN=128): Q (pre-scaled log2(e)/8) / K -> [B,H,S,64] bf16; V -> V^T [B,H,64,S].
// MODE 1 (BN=64):  fp32 out + bias, row-major (512 blocks = 2/CU).
#define QSCALE 0.1803368801111244f   // (1/8) * log2(e): softmax uses exp2
template <int MODE>
__global__ __launch_bounds__(256, 2) void gemm_bt(
    const unsigned short* __restrict__ A,   // [M,K] bf16 bits
    const unsigned short* __restrict__ B,   // [N,K] bf16 bits
    unsigned short* __restrict__ qo, unsigned short* __restrict__ ko,
    unsigned short* __restrict__ vo,        // vo is V^T [B,H,64,SEQ]
    float* __restrict__ co, const float* __restrict__ bias,
    int M, int N, int K) {
  constexpr int BN = (MODE == 0) ? 128 : 64;
  constexpr int TJ = BN / 32;               // 16-wide n-tiles per wave
  constexpr int RB = BN * 4 / 256;          // B staging rounds per sub-tile (2 or 1)
  __shared__ __align__(16) unsigned short As[2][128 * 32];
  __shared__ __align__(16) unsigned short Bs[2][BN * 32];

  const int tid  = threadIdx.x;
  const int lane = tid & 63;
  const int wave = tid >> 6;
  const int l15  = lane & 15;
  const int quad = lane >> 4;
  const int wm   = (wave >> 1) * 64;
  const int wn   = (wave & 1) * (BN / 2);
  const int m0   = blockIdx.x * 128;
  const int n0   = blockIdx.y * BN;

  f32x4 acc[4][TJ];
#pragma unroll
  for (int a = 0; a < 4; ++a)
#pragma unroll
    for (int b = 0; b < TJ; ++b) acc[a][b] = f32x4{0.f, 0.f, 0.f, 0.f};

  for (int k0 = 0; k0 < K; k0 += 64) {
    __syncthreads();
#pragma unroll
    for (int h = 0; h < 2; ++h) {
      const int kh = k0 + h * 32;
#pragma unroll
      for (int s = 0; s < 2; ++s) {           // A: 512 16B chunks / 256 threads
        const int c   = tid + s * 256;
        const int row = c >> 2;
        const int col = (c & 3) * 8;
        unsigned short* lA = As[h] + ((size_t)wave * 64 + s * 256) * 8;
        async_copy16(A + (size_t)(m0 + row) * K + kh + col, lA);
      }
#pragma unroll
      for (int s = 0; s < RB; ++s) {          // B: BN*4 chunks
        const int c   = tid + s * 256;
        const int row = c >> 2;
        const int col = (c & 3) * 8;
        unsigned short* lB = Bs[h] + ((size_t)wave * 64 + s * 256) * 8;
        async_copy16(B + (size_t)(n0 + row) * K + kh + col, lB);
      }
    }
    __syncthreads();

#pragma unroll
    for (int h = 0; h < 2; ++h) {
      bf16x8 af[4], bfr[TJ];
#pragma unroll
      for (int t = 0; t < 4; ++t)
        af[t]  = *reinterpret_cast<const bf16x8*>(As[h] + (wm + t * 16 + l15) * 32 + quad * 8);
#pragma unroll
      for (int t = 0; t < TJ; ++t)
        bfr[t] = *reinterpret_cast<const bf16x8*>(Bs[h] + (wn + t * 16 + l15) * 32 + quad * 8);
#pragma unroll
      for (int ti = 0; ti < 4; ++ti)
#pragma unroll
        for (int tj = 0; tj < TJ; ++tj)
          acc[ti][tj] = __builtin_amdgcn_mfma_f32_16x16x32_bf16(af[ti], bfr[tj], acc[ti][tj], 0, 0, 0);
    }
  }

  // C/D layout: col = lane&15, row = quad*4 + reg (verified m89/m91)
#pragma unroll
  for (int ti = 0; ti < 4; ++ti) {
#pragma unroll
    for (int tj = 0; tj < TJ; ++tj) {
      const int mb = m0 + wm + ti * 16 + quad * 4;   // rows mb..mb+3
      const int n  = n0 + wn + tj * 16 + l15;
      if (MODE == 0) {
        const int which = n >> 10;          // 0:q 1:k 2:v
        const int n1 = n & 1023;
        const int h = n1 >> 6, d = n1 & 63;
        const int b = mb >> 11, s = mb & 2047;
        if (which == 0) {
          const size_t idx = ((size_t)(b * NH + h) * SEQ + s) * HDIM + d;
#pragma unroll
          for (int r = 0; r < 4; ++r) qo[idx + (size_t)r * HDIM] = f2bf(acc[ti][tj][r] * QSCALE);
        } else if (which == 1) {
          const size_t idx = ((size_t)(b * NH + h) * SEQ + s) * HDIM + d;
#pragma unroll
          for (int r = 0; r < 4; ++r) ko[idx + (size_t)r * HDIM] = f2bf(acc[ti][tj][r]);
        } else {
          // V^T: [b,h,d,s] — 4 consecutive s per lane -> packed 8B store
          const size_t idx = ((size_t)(b * NH + h) * HDIM + d) * SEQ + s;
          uint2 pk;
          pk.x = pk2bf(acc[ti][tj][0], acc[ti][tj][1]);
          pk.y = pk2bf(acc[ti][tj][2], acc[ti][tj][3]);
          *reinterpret_cast<uint2*>(vo + idx) = pk;
        }
      } else {
#pragma unroll
        for (int r = 0; r < 4; ++r)
          co[(size_t)(mb + r) * N + n] = acc[ti][tj][r] + bias[n];
      }
    }
  }
}

// ---------------------------------------------------------------- MFMA flash attention
// R12 = R10's flash verbatim (best measured: 47 us). R11's DMA+source-swizzle variant
// regressed (uncoalesced global reads: FETCH +3 MB, WRITE +10 MB, 51 us) — reverted.
// Single-buffer LDS (KST=72 pad), coalesced uint4 staging, SPLIT-K (uniform <=12-iter
// blocks, fixed-origin softmax m=0 -> linear partials), register PV (S^T C-layout ==
// 16x16x16 A-frag layout), fexp2, launch_bounds(256,8) -> VGPR 32, occupancy ~38%.
#define KST 72

__global__ __launch_bounds__(256, 8) void flash_attn_mfma(
    const unsigned short* __restrict__ Qb,   // [bh][s][64], pre-scaled by log2(e)/8
    const unsigned short* __restrict__ Kb,   // [bh][s][64]
    const unsigned short* __restrict__ Vtg,  // [bh][d][2048]  (V^T)
    unsigned short* __restrict__ ctx,        // [b][s][1024] bf16
    unsigned short* __restrict__ pO,         // [1536][64][64] bf16 partial O
    float* __restrict__ pL) {                // [1536][64] fp32 partial l
  __shared__ __align__(16) unsigned short Ks[64 * KST];
  __shared__ __align__(16) unsigned short Vt[64 * KST];

  const int tid  = threadIdx.x;
  const int bh   = blockIdx.y;
  const int lane = tid & 63;
  const int wave = tid >> 6;
  const int l15  = lane & 15;
  const int quad = lane >> 4;

  // map blockIdx.x -> (qt, chunk, nch)
  int qt, chunk, nch;
  {
    const int x = blockIdx.x;
    if (x < 12)      { qt = x;                 chunk = 0;            nch = 1; }
    else if (x < 36) { qt = 12 + (x - 12) / 2; chunk = (x - 12) % 2; nch = 2; }
    else             { qt = 24 + (x - 36) / 3; chunk = (x - 36) % 3; nch = 3; }
  }
  const int q0 = qt * 64;
  const int c0 = chunk * 12;
  const int c1 = min(qt, c0 + 11);

  const size_t baseQK = (size_t)bh * SEQ * HDIM;
  const size_t baseV  = (size_t)bh * HDIM * SEQ;

  // staging geometry: 256 threads cover a 64x64 bf16 tile in 2 rounds of uint4
  const int srow = tid >> 3;          // 0..31
  const int scol = (tid & 7) * 8;     // 0..56

  // Q fragments (B-operand of S^T): lane holds Q[q = q0+wave*16+l15][k = s*32+quad*8+j]
  bf16x8 qf[2];
  {
    const unsigned short* qp = Qb + baseQK + (size_t)(q0 + wave * 16 + l15) * HDIM + quad * 8;
    qf[0] = *reinterpret_cast<const bf16x8*>(qp);
    qf[1] = *reinterpret_cast<const bf16x8*>(qp + 32);
  }

  float l_acc = 0.f;   // per-lane partial sum of P (q = l15, keys quad*4+r per subtile)
  f32x4 o[4];          // o[td][r] = O[q=wave*16+quad*4+r][d=td*16+l15]  (un-normalized)
#pragma unroll
  for (int td = 0; td < 4; ++td) o[td] = f32x4{0.f, 0.f, 0.f, 0.f};

  for (int kt = c0; kt <= c1; ++kt) {
    __syncthreads();   // everyone done reading the previous K/V tile
    {
      const uint4 k0v = *reinterpret_cast<const uint4*>(Kb + baseQK + (size_t)(kt * 64 + srow) * HDIM + scol);
      const uint4 k1v = *reinterpret_cast<const uint4*>(Kb + baseQK + (size_t)(kt * 64 + srow + 32) * HDIM + scol);
      const uint4 v0v = *reinterpret_cast<const uint4*>(Vtg + baseV + (size_t)srow * SEQ + kt * 64 + scol);
      const uint4 v1v = *reinterpret_cast<const uint4*>(Vtg + baseV + (size_t)(srow + 32) * SEQ + kt * 64 + scol);
      *reinterpret_cast<uint4*>(&Ks[srow * KST + scol]) = k0v;
      *reinterpret_cast<uint4*>(&Ks[(srow + 32) * KST + scol]) = k1v;
      *reinterpret_cast<uint4*>(&Vt[srow * KST + scol]) = v0v;
      *reinterpret_cast<uint4*>(&Vt[(srow + 32) * KST + scol]) = v1v;
    }
    __syncthreads();

    const int tmax = (kt == qt) ? wave : 3;   // diag: subtiles above wave strip fully masked

#pragma unroll
    for (int t = 0; t < 4; ++t) {
      if (t <= tmax) {
        // S^T subtile: c[r] = S[key = kt*64 + t*16 + quad*4 + r][q = l15]
        f32x4 c = f32x4{0.f, 0.f, 0.f, 0.f};
        const int krow = (t * 16 + l15) * KST;
        const bf16x8 kf0 = *reinterpret_cast<const bf16x8*>(&Ks[krow + quad * 8]);
        const bf16x8 kf1 = *reinterpret_cast<const bf16x8*>(&Ks[krow + 32 + quad * 8]);
        c = __builtin_amdgcn_mfma_f32_16x16x32_bf16(kf0, qf[0], c, 0, 0, 0);
        c = __builtin_amdgcn_mfma_f32_16x16x32_bf16(kf1, qf[1], c, 0, 0, 0);
        if (kt == qt && t == wave) {   // partial (diagonal) subtile: mask key > q
#pragma unroll
          for (int r = 0; r < 4; ++r)
            if (quad * 4 + r > l15) c[r] = -INFINITY;
        }

        // fixed-origin softmax (p = exp2(s), exp2(-inf)=0) -> A-frag IN REGISTERS
        const float p0 = fexp2(c[0]);
        const float p1 = fexp2(c[1]);
        const float p2 = fexp2(c[2]);
        const float p3 = fexp2(c[3]);
        l_acc += (p0 + p1) + (p2 + p3);
        union { uint2 u; short4v s; } pf;
        pf.u.x = pk2bf(p0, p1);
        pf.u.y = pk2bf(p2, p3);

        // O += P·V  (16x16x16: A m=q=l15, k=key=quad*4+j — exactly what this lane holds;
        //            B n=d=l15, k=key=quad*4+j — b64 read from V^T rows)
#pragma unroll
        for (int td = 0; td < 4; ++td) {
          const short4v vf = *reinterpret_cast<const short4v*>(
              &Vt[(td * 16 + l15) * KST + t * 16 + quad * 4]);
          o[td] = mfma16(pf.s, vf, o[td]);
        }
      }
    }
  }

  // l reduction across the 4 lanes sharing l15 (within this chunk's key range)
  float l_s = l_acc;
  l_s += __shfl_xor(l_s, 16, 64);
  l_s += __shfl_xor(l_s, 32, 64);

  if (nch == 1) {
    // single chunk: normalize and write ctx directly
    const float linv = 1.f / l_s;   // for q = wave*16 + l15
    const int b = bh >> 4, h = bh & 15;
#pragma unroll
    for (int r = 0; r < 4; ++r) {
      const float lr = __shfl(linv, quad * 4 + r, 64);
      const int sr = q0 + wave * 16 + quad * 4 + r;
      const size_t ob = (size_t)(b * SEQ + sr) * DM + h * HDIM + l15;
#pragma unroll
      for (int td = 0; td < 4; ++td)
        ctx[ob + td * 16] = f2bf(o[td][r] * lr);
    }
  } else {
    // partial: pidx = bh*48 + pbase(qt) + chunk
    const int pb = (qt < 24) ? 2 * (qt - 12) : 24 + 3 * (qt - 24);
    const int pidx = bh * 48 + pb + chunk;
    if (quad == 0) pL[pidx * 64 + wave * 16 + l15] = l_s;
    unsigned short* po = pO + (size_t)pidx * 4096;
#pragma unroll
    for (int r = 0; r < 4; ++r) {
      const int ql = wave * 16 + quad * 4 + r;
#pragma unroll
      for (int td = 0; td < 4; ++td)
        po[ql * 64 + td * 16 + l15] = f2bf(o[td][r]);
    }
  }
}

// ---------------------------------------------------------------- partial combine + normalize
__global__ __launch_bounds__(256, 8) void attn_reduce(
    const unsigned short* __restrict__ pO, const float* __restrict__ pL,
    unsigned short* __restrict__ ctx) {
  const int x = blockIdx.x;
  int qt, pb, nch;
  if (x < 12) { qt = 12 + x; pb = 2 * x;            nch = 2; }
  else        { qt = 24 + (x - 12); pb = 24 + 3 * (x - 12); nch = 3; }
  const int bh = blockIdx.y;
  const int b = bh >> 4, h = bh & 15;
  const int pidx = bh * 48 + pb;

  const int tid = threadIdx.x;
  const int ql  = tid >> 2;            // 0..63
  const int d0  = (tid & 3) * 16;      // 0,16,32,48

  float acc[16];
#pragma unroll
  for (int e = 0; e < 16; ++e) acc[e] = 0.f;
  float lsum = 0.f;

  for (int c = 0; c < nch; ++c) {
    lsum += pL[(pidx + c) * 64 + ql];
    const unsigned short* src = pO + (size_t)(pidx + c) * 4096 + ql * 64 + d0;
    const uint4 v0 = *reinterpret_cast<const uint4*>(src);
    const uint4 v1 = *reinterpret_cast<const uint4*>(src + 8);
    const unsigned short* u = reinterpret_cast<const unsigned short*>(&v0);
    const unsigned short* w = reinterpret_cast<const unsigned short*>(&v1);
#pragma unroll
    for (int e = 0; e < 8; ++e) { acc[e] += bf2f(u[e]); acc[8 + e] += bf2f(w[e]); }
  }

  const float linv = 1.f / lsum;
  unsigned int outw[8];
#pragma unroll
  for (int e = 0; e < 8; ++e)
    outw[e] = pk2bf(acc[2 * e] * linv, acc[2 * e + 1] * linv);
  unsigned short* dst = ctx + (size_t)(b * SEQ + qt * 64 + ql) * DM + h * HDIM + d0;
  *reinterpret_cast<uint4*>(dst)     = *reinterpret_cast<uint4*>(&outw[0]);
  *reinterpret_cast<uint4*>(dst + 8) = *reinterpret_cast<uint4*>(&outw[4]);
}

// ---------------------------------------------------------------- launch
extern "C" void kernel_launch(void* const* d_in, const int* in_sizes, int n_in,
                              void* d_out, int out_size, void* d_ws, size_t ws_size,
                              hipStream_t stream) {
  const float* x  = (const float*)d_in[0];
  const float* wq = (const float*)d_in[1];
  const float* wk = (const float*)d_in[2];
  const float* wv = (const float*)d_in[3];
  const float* wo = (const float*)d_in[4];
  const float* bo = (const float*)d_in[5];
  float* out = (float*)d_out;

  // ws layout (48 MB total). [0,14M) is xb+wqkvb during projections, then REUSED
  // for attention partials (pO 12 MB + pL 0.4 MB) — stream-ordered, no overlap in time.
  char* ws = (char*)d_ws;
  unsigned short* xb    = (unsigned short*)(ws);                    // [4096,1024]    8 MB
  unsigned short* wqkvb = (unsigned short*)(ws + (8ull  << 20));    // [3072,1024]    6 MB
  unsigned short* wob   = (unsigned short*)(ws + (14ull << 20));    // [1024,1024]    2 MB
  unsigned short* Qb    = (unsigned short*)(ws + (16ull << 20));    // [32,2048,64]   8 MB (pre-scaled)
  unsigned short* Kb    = (unsigned short*)(ws + (24ull << 20));    // [32,2048,64]   8 MB
  unsigned short* Vtg   = (unsigned short*)(ws + (32ull << 20));    // [32,64,2048]   8 MB (V^T)
  unsigned short* ctxb  = (unsigned short*)(ws + (40ull << 20));    // [4096,1024]    8 MB
  unsigned short* pO    = (unsigned short*)(ws);                    // [1536,64,64]  12 MB
  float*          pL    = (float*)(ws + (12ull << 20));             // [1536,64]    0.4 MB

  cast_all<<<8192, 256, 0, stream>>>(x, wq, wk, wv, wo, xb, wqkvb, wob);

  dim3 g1(MTOK / 128, (3 * DM) / 128);   // 32 x 24
  gemm_bt<0><<<g1, 256, 0, stream>>>(xb, wqkvb, Qb, Kb, Vtg, nullptr, nullptr,
                                     MTOK, 3 * DM, DM);

  dim3 g2(60, NB * NH);                  // 60 chunk-blocks per bh
  flash_attn_mfma<<<g2, 256, 0, stream>>>(Qb, Kb, Vtg, ctxb, pO, pL);

  dim3 gr(20, NB * NH);                  // multi-chunk q-tiles only
  attn_reduce<<<gr, 256, 0, stream>>>(pO, pL, ctxb);

  dim3 g3(MTOK / 128, DM / 64);          // 32 x 16  (128x64 tiles -> 512 blocks)
  gemm_bt<1><<<g3, 256, 0, stream>>>(ctxb, wob, nullptr, nullptr, nullptr, out, bo,
                                     MTOK, DM, DM);
}

// Round 13
// 183.208 us; speedup vs baseline: 1.0168x; 1.0168x over previous
//
#include <hip/hip_runtime.h>
#include <hip/hip_bf16.h>
#include <stdint.h>
#include <math.h>

// Problem constants (fixed by the reference)
#define NH   16
#define HDIM 64
#define SEQ  2048
#define DM   1024
#define NB   2
#define MTOK (NB * SEQ)   // 4096

typedef __bf16 bf16x8 __attribute__((ext_vector_type(8)));  // 4 VGPRs, MFMA A/B frag
typedef __bf16 bf16x4 __attribute__((ext_vector_type(4)));  // 2 VGPRs, 16x16x16 frag
typedef short  short4v __attribute__((ext_vector_type(4)));
typedef float  f32x4  __attribute__((ext_vector_type(4)));  // MFMA C/D frag

__device__ __forceinline__ unsigned short f2bf(float f) {
  union { float f; unsigned int u; } c; c.f = f;
  unsigned int u = c.u;
  return (unsigned short)((u + 0x7FFFu + ((u >> 16) & 1u)) >> 16);  // RNE
}
__device__ __forceinline__ float bf2f(unsigned short s) {
  union { unsigned int u; float f; } c; c.u = ((unsigned int)s) << 16;
  return c.f;
}
__device__ __forceinline__ unsigned int pk2bf(float a, float b) {   // packed RNE cvt
  __hip_bfloat162 h = __float22bfloat162_rn(float2{a, b});
  return *reinterpret_cast<unsigned int*>(&h);
}

// raw v_exp_f32 (base-2): OCML exp2f carries edge handling; scores are small fp32,
// exp2(-inf)=0 preserved. R10-proven: VALUBusy 51 -> 38.
__device__ __forceinline__ float fexp2(float x) {
#if __has_builtin(__builtin_amdgcn_exp2f)
  return __builtin_amdgcn_exp2f(x);
#else
  return exp2f(x);
#endif
}

// 16x16x16 bf16 MFMA with builtin-name portability (gfx950 bf16-typed vs legacy _1k)
__device__ __forceinline__ f32x4 mfma16(short4v a, short4v b, f32x4 c) {
#if __has_builtin(__builtin_amdgcn_mfma_f32_16x16x16_bf16)
  return __builtin_amdgcn_mfma_f32_16x16x16_bf16(
      __builtin_bit_cast(bf16x4, a), __builtin_bit_cast(bf16x4, b), c, 0, 0, 0);
#else
  return __builtin_amdgcn_mfma_f32_16x16x16bf16_1k(a, b, c, 0, 0, 0);
#endif
}

// async global->LDS, 16B per lane. LDS dest = wave-uniform base + lane*16 (m104/m108).
__device__ __forceinline__ void async_copy16(const void* g, void* l) {
  __builtin_amdgcn_global_load_lds((__attribute__((address_space(1))) void*)g,
                                   (__attribute__((address_space(3))) void*)l,
                                   16, 0, 0);
}

// ---------------------------------------------------------------- fused casts (1 launch, exact grid)
__global__ void cast_all(const float* __restrict__ x,  const float* __restrict__ wq,
                         const float* __restrict__ wk, const float* __restrict__ wv,
                         const float* __restrict__ wo,
                         unsigned short* __restrict__ xb,
                         unsigned short* __restrict__ wqkvb,
                         unsigned short* __restrict__ wob) {
  const int i = blockIdx.x * 256 + threadIdx.x;
  float4 v;
  uint2* dstp;
  int idx;
  if (i < (1 << 20)) {
    v = reinterpret_cast<const float4*>(x)[i];
    dstp = reinterpret_cast<uint2*>(xb); idx = i;
  } else {
    const int j = i - (1 << 20);
    const int seg = j >> 18;            // 0..3
    idx = j & ((1 << 18) - 1);
    const float* w = (seg == 0) ? wq : (seg == 1) ? wk : (seg == 2) ? wv : wo;
    v = reinterpret_cast<const float4*>(w)[idx];
    if (seg < 3) { dstp = reinterpret_cast<uint2*>(wqkvb); idx += seg * (1 << 18); }
    else         { dstp = reinterpret_cast<uint2*>(wob); }
  }
  uint2 o;
  o.x = pk2bf(v.x, v.y); o.y = pk2bf(v.z, v.w);
  dstp[idx] = o;
}

// ---------------------------------------------------------------- GEMM (NT): C[m,n] = sum_k A[m,k]*B[n,k]
// m97 structure, BK=32 single-stage (R8/R11 proven config; BK=64 and (256,3) variants
// were noise-to-negative across R9-R12 — barrier count is not this kernel's limiter).
// MODE 0 (BN=128): Q (pre-scaled log2(e)/8) / K -> [B,H,S,64] bf16; V -> V^T [B,H,64,S].
// MODE 1 (BN=64):  fp32 out + bias, row-major (512 blocks = 2/CU).
#define QSCALE 0.1803368801111244f   // (1/8) * log2(e): softmax uses exp2
template <int MODE>
__global__ __launch_bounds__(256, 2) void gemm_bt(
    const unsigned short* __restrict__ A,   // [M,K] bf16 bits
    const unsigned short* __restrict__ B,   // [N,K] bf16 bits
    unsigned short* __restrict__ qo, unsigned short* __restrict__ ko,
    unsigned short* __restrict__ vo,        // vo is V^T [B,H,64,SEQ]
    float* __restrict__ co, const float* __restrict__ bias,
    int M, int N, int K) {
  constexpr int BN = (MODE == 0) ? 128 : 64;
  constexpr int TJ = BN / 32;               // 16-wide n-tiles per wave
  constexpr int RB = BN * 4 / 256;          // B staging rounds (2 or 1)
  __shared__ __align__(16) unsigned short As[128 * 32];
  __shared__ __align__(16) unsigned short Bs[BN * 32];

  const int tid  = threadIdx.x;
  const int lane = tid & 63;
  const int wave = tid >> 6;
  const int l15  = lane & 15;
  const int quad = lane >> 4;
  const int wm   = (wave >> 1) * 64;
  const int wn   = (wave & 1) * (BN / 2);
  const int m0   = blockIdx.x * 128;
  const int n0   = blockIdx.y * BN;

  f32x4 acc[4][TJ];
#pragma unroll
  for (int a = 0; a < 4; ++a)
#pragma unroll
    for (int b = 0; b < TJ; ++b) acc[a][b] = f32x4{0.f, 0.f, 0.f, 0.f};

  for (int k0 = 0; k0 < K; k0 += 32) {
    __syncthreads();
#pragma unroll
    for (int s = 0; s < 2; ++s) {             // A: 512 16B chunks / 256 threads
      const int c   = tid + s * 256;
      const int row = c >> 2;
      const int col = (c & 3) * 8;
      unsigned short* lA = As + ((size_t)wave * 64 + s * 256) * 8;
      async_copy16(A + (size_t)(m0 + row) * K + k0 + col, lA);
    }
#pragma unroll
    for (int s = 0; s < RB; ++s) {            // B: BN*4 chunks
      const int c   = tid + s * 256;
      const int row = c >> 2;
      const int col = (c & 3) * 8;
      unsigned short* lB = Bs + ((size_t)wave * 64 + s * 256) * 8;
      async_copy16(B + (size_t)(n0 + row) * K + k0 + col, lB);
    }
    __syncthreads();

    bf16x8 af[4], bfr[TJ];
#pragma unroll
    for (int t = 0; t < 4; ++t)
      af[t]  = *reinterpret_cast<const bf16x8*>(As + (wm + t * 16 + l15) * 32 + quad * 8);
#pragma unroll
    for (int t = 0; t < TJ; ++t)
      bfr[t] = *reinterpret_cast<const bf16x8*>(Bs + (wn + t * 16 + l15) * 32 + quad * 8);
#pragma unroll
    for (int ti = 0; ti < 4; ++ti)
#pragma unroll
      for (int tj = 0; tj < TJ; ++tj)
        acc[ti][tj] = __builtin_amdgcn_mfma_f32_16x16x32_bf16(af[ti], bfr[tj], acc[ti][tj], 0, 0, 0);
  }

  // C/D layout: col = lane&15, row = quad*4 + reg (verified m89/m91)
#pragma unroll
  for (int ti = 0; ti < 4; ++ti) {
#pragma unroll
    for (int tj = 0; tj < TJ; ++tj) {
      const int mb = m0 + wm + ti * 16 + quad * 4;   // rows mb..mb+3
      const int n  = n0 + wn + tj * 16 + l15;
      if (MODE == 0) {
        const int which = n >> 10;          // 0:q 1:k 2:v
        const int n1 = n & 1023;
        const int h = n1 >> 6, d = n1 & 63;
        const int b = mb >> 11, s = mb & 2047;
        if (which == 0) {
          const size_t idx = ((size_t)(b * NH + h) * SEQ + s) * HDIM + d;
#pragma unroll
          for (int r = 0; r < 4; ++r) qo[idx + (size_t)r * HDIM] = f2bf(acc[ti][tj][r] * QSCALE);
        } else if (which == 1) {
          const size_t idx = ((size_t)(b * NH + h) * SEQ + s) * HDIM + d;
#pragma unroll
          for (int r = 0; r < 4; ++r) ko[idx + (size_t)r * HDIM] = f2bf(acc[ti][tj][r]);
        } else {
          // V^T: [b,h,d,s] — 4 consecutive s per lane -> packed 8B store
          const size_t idx = ((size_t)(b * NH + h) * HDIM + d) * SEQ + s;
          uint2 pk;
          pk.x = pk2bf(acc[ti][tj][0], acc[ti][tj][1]);
          pk.y = pk2bf(acc[ti][tj][2], acc[ti][tj][3]);
          *reinterpret_cast<uint2*>(vo + idx) = pk;
        }
      } else {
#pragma unroll
        for (int r = 0; r < 4; ++r)
          co[(size_t)(mb + r) * N + n] = acc[ti][tj][r] + bias[n];
      }
    }
  }
}

// ---------------------------------------------------------------- MFMA flash attention
// R13 = R12 flash + REGISTER PREFETCH pipeline (R4's idea, now spill-safe: base kernel
// is 32 VGPRs; prefetch adds ~24; launch_bounds(256,6) caps at 85 — ample headroom,
// 6 blocks/CU capacity). Next tile's 4 uint4 loads issue right after barrier B, land
// during the ~600-cyc compute phase; the ds_writes at the next iter top find them
// resident — removes the in-line global latency from the per-iter critical path.
// SPLIT-K (uniform <=12-iter chunks, fixed-origin softmax m=0 -> linear partials) +
// register PV (S^T C-layout == 16x16x16 A-frag layout) + fexp2. KST=72 pad (2-way free).
#define KST 72

__global__ __launch_bounds__(256, 6) void flash_attn_mfma(
    const unsigned short* __restrict__ Qb,   // [bh][s][64], pre-scaled by log2(e)/8
    const unsigned short* __restrict__ Kb,   // [bh][s][64]
    const unsigned short* __restrict__ Vtg,  // [bh][d][2048]  (V^T)
    unsigned short* __restrict__ ctx,        // [b][s][1024] bf16
    unsigned short* __restrict__ pO,         // [1536][64][64] bf16 partial O
    float* __restrict__ pL) {                // [1536][64] fp32 partial l
  __shared__ __align__(16) unsigned short Ks[64 * KST];
  __shared__ __align__(16) unsigned short Vt[64 * KST];

  const int tid  = threadIdx.x;
  const int bh   = blockIdx.y;
  const int lane = tid & 63;
  const int wave = tid >> 6;
  const int l15  = lane & 15;
  const int quad = lane >> 4;

  // map blockIdx.x -> (qt, chunk, nch)
  int qt, chunk, nch;
  {
    const int x = blockIdx.x;
    if (x < 12)      { qt = x;                 chunk = 0;            nch = 1; }
    else if (x < 36) { qt = 12 + (x - 12) / 2; chunk = (x - 12) % 2; nch = 2; }
    else             { qt = 24 + (x - 36) / 3; chunk = (x - 36) % 3; nch = 3; }
  }
  const int q0 = qt * 64;
  const int c0 = chunk * 12;
  const int c1 = min(qt, c0 + 11);

  const size_t baseQK = (size_t)bh * SEQ * HDIM;
  const size_t baseV  = (size_t)bh * HDIM * SEQ;

  // staging geometry: 256 threads cover a 64x64 bf16 tile in 2 rounds of uint4
  const int srow = tid >> 3;          // 0..31
  const int scol = (tid & 7) * 8;     // 0..56

  // prefetch pointers (advance by one k-tile per iteration)
  const unsigned short* kp = Kb + baseQK + (size_t)(c0 * 64 + srow) * HDIM + scol;
  const unsigned short* vp = Vtg + baseV + (size_t)srow * SEQ + c0 * 64 + scol;

  // Q fragments (B-operand of S^T): lane holds Q[q = q0+wave*16+l15][k = s*32+quad*8+j]
  bf16x8 qf[2];
  {
    const unsigned short* qp = Qb + baseQK + (size_t)(q0 + wave * 16 + l15) * HDIM + quad * 8;
    qf[0] = *reinterpret_cast<const bf16x8*>(qp);
    qf[1] = *reinterpret_cast<const bf16x8*>(qp + 32);
  }

  float l_acc = 0.f;   // per-lane partial sum of P (q = l15, keys quad*4+r per subtile)
  f32x4 o[4];          // o[td][r] = O[q=wave*16+quad*4+r][d=td*16+l15]  (un-normalized)
#pragma unroll
  for (int td = 0; td < 4; ++td) o[td] = f32x4{0.f, 0.f, 0.f, 0.f};

  // prologue: prefetch tile c0 into registers
  uint4 rk0 = *reinterpret_cast<const uint4*>(kp);
  uint4 rk1 = *reinterpret_cast<const uint4*>(kp + 32 * HDIM);
  uint4 rv0 = *reinterpret_cast<const uint4*>(vp);
  uint4 rv1 = *reinterpret_cast<const uint4*>(vp + 32 * SEQ);
  kp += 64 * HDIM; vp += 64;

  for (int kt = c0; kt <= c1; ++kt) {
    __syncthreads();   // barrier A: everyone done reading the previous K/V tile
    *reinterpret_cast<uint4*>(&Ks[srow * KST + scol])        = rk0;
    *reinterpret_cast<uint4*>(&Ks[(srow + 32) * KST + scol]) = rk1;
    *reinterpret_cast<uint4*>(&Vt[srow * KST + scol])        = rv0;
    *reinterpret_cast<uint4*>(&Vt[(srow + 32) * KST + scol]) = rv1;
    __syncthreads();   // barrier B: tile kt visible

    if (kt < c1) {     // prefetch kt+1; latency hides behind the compute below
      rk0 = *reinterpret_cast<const uint4*>(kp);
      rk1 = *reinterpret_cast<const uint4*>(kp + 32 * HDIM);
      rv0 = *reinterpret_cast<const uint4*>(vp);
      rv1 = *reinterpret_cast<const uint4*>(vp + 32 * SEQ);
      kp += 64 * HDIM; vp += 64;
    }

    const int tmax = (kt == qt) ? wave : 3;   // diag: subtiles above wave strip fully masked

#pragma unroll
    for (int t = 0; t < 4; ++t) {
      if (t <= tmax) {
        // S^T subtile: c[r] = S[key = kt*64 + t*16 + quad*4 + r][q = l15]
        f32x4 c = f32x4{0.f, 0.f, 0.f, 0.f};
        const int krow = (t * 16 + l15) * KST;
        const bf16x8 kf0 = *reinterpret_cast<const bf16x8*>(&Ks[krow + quad * 8]);
        const bf16x8 kf1 = *reinterpret_cast<const bf16x8*>(&Ks[krow + 32 + quad * 8]);
        c = __builtin_amdgcn_mfma_f32_16x16x32_bf16(kf0, qf[0], c, 0, 0, 0);
        c = __builtin_amdgcn_mfma_f32_16x16x32_bf16(kf1, qf[1], c, 0, 0, 0);
        if (kt == qt && t == wave) {   // partial (diagonal) subtile: mask key > q
#pragma unroll
          for (int r = 0; r < 4; ++r)
            if (quad * 4 + r > l15) c[r] = -INFINITY;
        }

        // fixed-origin softmax (p = exp2(s), exp2(-inf)=0) -> A-frag IN REGISTERS
        const float p0 = fexp2(c[0]);
        const float p1 = fexp2(c[1]);
        const float p2 = fexp2(c[2]);
        const float p3 = fexp2(c[3]);
        l_acc += (p0 + p1) + (p2 + p3);
        union { uint2 u; short4v s; } pf;
        pf.u.x = pk2bf(p0, p1);
        pf.u.y = pk2bf(p2, p3);

        // O += P·V  (16x16x16: A m=q=l15, k=key=quad*4+j — exactly what this lane holds;
        //            B n=d=l15, k=key=quad*4+j — b64 read from V^T rows)
#pragma unroll
        for (int td = 0; td < 4; ++td) {
          const short4v vf = *reinterpret_cast<const short4v*>(
              &Vt[(td * 16 + l15) * KST + t * 16 + quad * 4]);
          o[td] = mfma16(pf.s, vf, o[td]);
        }
      }
    }
  }

  // l reduction across the 4 lanes sharing l15 (within this chunk's key range)
  float l_s = l_acc;
  l_s += __shfl_xor(l_s, 16, 64);
  l_s += __shfl_xor(l_s, 32, 64);

  if (nch == 1) {
    // single chunk: normalize and write ctx directly
    const float linv = 1.f / l_s;   // for q = wave*16 + l15
    const int b = bh >> 4, h = bh & 15;
#pragma unroll
    for (int r = 0; r < 4; ++r) {
      const float lr = __shfl(linv, quad * 4 + r, 64);
      const int sr = q0 + wave * 16 + quad * 4 + r;
      const size_t ob = (size_t)(b * SEQ + sr) * DM + h * HDIM + l15;
#pragma unroll
      for (int td = 0; td < 4; ++td)
        ctx[ob + td * 16] = f2bf(o[td][r] * lr);
    }
  } else {
    // partial: pidx = bh*48 + pbase(qt) + chunk
    const int pb = (qt < 24) ? 2 * (qt - 12) : 24 + 3 * (qt - 24);
    const int pidx = bh * 48 + pb + chunk;
    if (quad == 0) pL[pidx * 64 + wave * 16 + l15] = l_s;
    unsigned short* po = pO + (size_t)pidx * 4096;
#pragma unroll
    for (int r = 0; r < 4; ++r) {
      const int ql = wave * 16 + quad * 4 + r;
#pragma unroll
      for (int td = 0; td < 4; ++td)
        po[ql * 64 + td * 16 + l15] = f2bf(o[td][r]);
    }
  }
}

// ---------------------------------------------------------------- partial combine + normalize
__global__ __launch_bounds__(256, 8) void attn_reduce(
    const unsigned short* __restrict__ pO, const float* __restrict__ pL,
    unsigned short* __restrict__ ctx) {
  const int x = blockIdx.x;
  int qt, pb, nch;
  if (x < 12) { qt = 12 + x; pb = 2 * x;            nch = 2; }
  else        { qt = 24 + (x - 12); pb = 24 + 3 * (x - 12); nch = 3; }
  const int bh = blockIdx.y;
  const int b = bh >> 4, h = bh & 15;
  const int pidx = bh * 48 + pb;

  const int tid = threadIdx.x;
  const int ql  = tid >> 2;            // 0..63
  const int d0  = (tid & 3) * 16;      // 0,16,32,48

  float acc[16];
#pragma unroll
  for (int e = 0; e < 16; ++e) acc[e] = 0.f;
  float lsum = 0.f;

  for (int c = 0; c < nch; ++c) {
    lsum += pL[(pidx + c) * 64 + ql];
    const unsigned short* src = pO + (size_t)(pidx + c) * 4096 + ql * 64 + d0;
    const uint4 v0 = *reinterpret_cast<const uint4*>(src);
    const uint4 v1 = *reinterpret_cast<const uint4*>(src + 8);
    const unsigned short* u = reinterpret_cast<const unsigned short*>(&v0);
    const unsigned short* w = reinterpret_cast<const unsigned short*>(&v1);
#pragma unroll
    for (int e = 0; e < 8; ++e) { acc[e] += bf2f(u[e]); acc[8 + e] += bf2f(w[e]); }
  }

  const float linv = 1.f / lsum;
  unsigned int outw[8];
#pragma unroll
  for (int e = 0; e < 8; ++e)
    outw[e] = pk2bf(acc[2 * e] * linv, acc[2 * e + 1] * linv);
  unsigned short* dst = ctx + (size_t)(b * SEQ + qt * 64 + ql) * DM + h * HDIM + d0;
  *reinterpret_cast<uint4*>(dst)     = *reinterpret_cast<uint4*>(&outw[0]);
  *reinterpret_cast<uint4*>(dst + 8) = *reinterpret_cast<uint4*>(&outw[4]);
}

// ---------------------------------------------------------------- launch
extern "C" void kernel_launch(void* const* d_in, const int* in_sizes, int n_in,
                              void* d_out, int out_size, void* d_ws, size_t ws_size,
                              hipStream_t stream) {
  const float* x  = (const float*)d_in[0];
  const float* wq = (const float*)d_in[1];
  const float* wk = (const float*)d_in[2];
  const float* wv = (const float*)d_in[3];
  const float* wo = (const float*)d_in[4];
  const float* bo = (const float*)d_in[5];
  float* out = (float*)d_out;

  // ws layout (48 MB total). [0,14M) is xb+wqkvb during projections, then REUSED
  // for attention partials (pO 12 MB + pL 0.4 MB) — stream-ordered, no overlap in time.
  char* ws = (char*)d_ws;
  unsigned short* xb    = (unsigned short*)(ws);                    // [4096,1024]    8 MB
  unsigned short* wqkvb = (unsigned short*)(ws + (8ull  << 20));    // [3072,1024]    6 MB
  unsigned short* wob   = (unsigned short*)(ws + (14ull << 20));    // [1024,1024]    2 MB
  unsigned short* Qb    = (unsigned short*)(ws + (16ull << 20));    // [32,2048,64]   8 MB (pre-scaled)
  unsigned short* Kb    = (unsigned short*)(ws + (24ull << 20));    // [32,2048,64]   8 MB
  unsigned short* Vtg   = (unsigned short*)(ws + (32ull << 20));    // [32,64,2048]   8 MB (V^T)
  unsigned short* ctxb  = (unsigned short*)(ws + (40ull << 20));    // [4096,1024]    8 MB
  unsigned short* pO    = (unsigned short*)(ws);                    // [1536,64,64]  12 MB
  float*          pL    = (float*)(ws + (12ull << 20));             // [1536,64]    0.4 MB

  cast_all<<<8192, 256, 0, stream>>>(x, wq, wk, wv, wo, xb, wqkvb, wob);

  dim3 g1(MTOK / 128, (3 * DM) / 128);   // 32 x 24
  gemm_bt<0><<<g1, 256, 0, stream>>>(xb, wqkvb, Qb, Kb, Vtg, nullptr, nullptr,
                                     MTOK, 3 * DM, DM);

  dim3 g2(60, NB * NH);                  // 60 chunk-blocks per bh
  flash_attn_mfma<<<g2, 256, 0, stream>>>(Qb, Kb, Vtg, ctxb, pO, pL);

  dim3 gr(20, NB * NH);                  // multi-chunk q-tiles only
  attn_reduce<<<gr, 256, 0, stream>>>(pO, pL, ctxb);

  dim3 g3(MTOK / 128, DM / 64);          // 32 x 16  (128x64 tiles -> 512 blocks)
  gemm_bt<1><<<g3, 256, 0, stream>>>(ctxb, wob, nullptr, nullptr, nullptr, out, bo,
                                     MTOK, DM, DM);
}

// Round 14
// 182.806 us; speedup vs baseline: 1.0190x; 1.0022x over previous
//
#include <hip/hip_runtime.h>
#include <hip/hip_bf16.h>
#include <stdint.h>
#include <math.h>

// Problem constants (fixed by the reference)
#define NH   16
#define HDIM 64
#define SEQ  2048
#define DM   1024
#define NB   2
#define MTOK (NB * SEQ)   // 4096

typedef __bf16 bf16x8 __attribute__((ext_vector_type(8)));  // 4 VGPRs, MFMA A/B frag
typedef __bf16 bf16x4 __attribute__((ext_vector_type(4)));  // 2 VGPRs, 16x16x16 frag
typedef short  short4v __attribute__((ext_vector_type(4)));
typedef float  f32x4  __attribute__((ext_vector_type(4)));  // MFMA C/D frag

__device__ __forceinline__ unsigned short f2bf(float f) {
  union { float f; unsigned int u; } c; c.f = f;
  unsigned int u = c.u;
  return (unsigned short)((u + 0x7FFFu + ((u >> 16) & 1u)) >> 16);  // RNE
}
__device__ __forceinline__ float bf2f(unsigned short s) {
  union { unsigned int u; float f; } c; c.u = ((unsigned int)s) << 16;
  return c.f;
}
__device__ __forceinline__ unsigned int pk2bf(float a, float b) {   // packed RNE cvt
  __hip_bfloat162 h = __float22bfloat162_rn(float2{a, b});
  return *reinterpret_cast<unsigned int*>(&h);
}

// raw v_exp_f32 (base-2): OCML exp2f carries edge handling; scores are small fp32,
// exp2(-inf)=0 preserved. R10-proven: VALUBusy 51 -> 38.
__device__ __forceinline__ float fexp2(float x) {
#if __has_builtin(__builtin_amdgcn_exp2f)
  return __builtin_amdgcn_exp2f(x);
#else
  return exp2f(x);
#endif
}

// 16x16x16 bf16 MFMA with builtin-name portability (gfx950 bf16-typed vs legacy _1k)
__device__ __forceinline__ f32x4 mfma16(short4v a, short4v b, f32x4 c) {
#if __has_builtin(__builtin_amdgcn_mfma_f32_16x16x16_bf16)
  return __builtin_amdgcn_mfma_f32_16x16x16_bf16(
      __builtin_bit_cast(bf16x4, a), __builtin_bit_cast(bf16x4, b), c, 0, 0, 0);
#else
  return __builtin_amdgcn_mfma_f32_16x16x16bf16_1k(a, b, c, 0, 0, 0);
#endif
}

// async global->LDS, 16B per lane. LDS dest = wave-uniform base + lane*16 (m104/m108).
__device__ __forceinline__ void async_copy16(const void* g, void* l) {
  __builtin_amdgcn_global_load_lds((__attribute__((address_space(1))) void*)g,
                                   (__attribute__((address_space(3))) void*)l,
                                   16, 0, 0);
}

// ---------------------------------------------------------------- fused casts (1 launch, exact grid)
__global__ void cast_all(const float* __restrict__ x,  const float* __restrict__ wq,
                         const float* __restrict__ wk, const float* __restrict__ wv,
                         const float* __restrict__ wo,
                         unsigned short* __restrict__ xb,
                         unsigned short* __restrict__ wqkvb,
                         unsigned short* __restrict__ wob) {
  const int i = blockIdx.x * 256 + threadIdx.x;
  float4 v;
  uint2* dstp;
  int idx;
  if (i < (1 << 20)) {
    v = reinterpret_cast<const float4*>(x)[i];
    dstp = reinterpret_cast<uint2*>(xb); idx = i;
  } else {
    const int j = i - (1 << 20);
    const int seg = j >> 18;            // 0..3
    idx = j & ((1 << 18) - 1);
    const float* w = (seg == 0) ? wq : (seg == 1) ? wk : (seg == 2) ? wv : wo;
    v = reinterpret_cast<const float4*>(w)[idx];
    if (seg < 3) { dstp = reinterpret_cast<uint2*>(wqkvb); idx += seg * (1 << 18); }
    else         { dstp = reinterpret_cast<uint2*>(wob); }
  }
  uint2 o;
  o.x = pk2bf(v.x, v.y); o.y = pk2bf(v.z, v.w);
  dstp[idx] = o;
}

// ---------------------------------------------------------------- GEMM (NT): C[m,n] = sum_k A[m,k]*B[n,k]
// m97 structure, BK=32 single-stage, (256,2) — the proven config (R8/R11); BK=64 and
// (256,3) were noise-to-negative (R9-R12).
// MODE 0 (BN=128): Q (pre-scaled log2(e)/8) / K -> [B,H,S,64] bf16; V -> V^T [B,H,64,S].
// MODE 1 (BN=64):  fp32 out + bias, row-major (512 blocks = 2/CU).
#define QSCALE 0.1803368801111244f   // (1/8) * log2(e): softmax uses exp2
template <int MODE>
__global__ __launch_bounds__(256, 2) void gemm_bt(
    const unsigned short* __restrict__ A,   // [M,K] bf16 bits
    const unsigned short* __restrict__ B,   // [N,K] bf16 bits
    unsigned short* __restrict__ qo, unsigned short* __restrict__ ko,
    unsigned short* __restrict__ vo,        // vo is V^T [B,H,64,SEQ]
    float* __restrict__ co, const float* __restrict__ bias,
    int M, int N, int K) {
  constexpr int BN = (MODE == 0) ? 128 : 64;
  constexpr int TJ = BN / 32;               // 16-wide n-tiles per wave
  constexpr int RB = BN * 4 / 256;          // B staging rounds (2 or 1)
  __shared__ __align__(16) unsigned short As[128 * 32];
  __shared__ __align__(16) unsigned short Bs[BN * 32];

  const int tid  = threadIdx.x;
  const int lane = tid & 63;
  const int wave = tid >> 6;
  const int l15  = lane & 15;
  const int quad = lane >> 4;
  const int wm   = (wave >> 1) * 64;
  const int wn   = (wave & 1) * (BN / 2);
  const int m0   = blockIdx.x * 128;
  const int n0   = blockIdx.y * BN;

  f32x4 acc[4][TJ];
#pragma unroll
  for (int a = 0; a < 4; ++a)
#pragma unroll
    for (int b = 0; b < TJ; ++b) acc[a][b] = f32x4{0.f, 0.f, 0.f, 0.f};

  for (int k0 = 0; k0 < K; k0 += 32) {
    __syncthreads();
#pragma unroll
    for (int s = 0; s < 2; ++s) {             // A: 512 16B chunks / 256 threads
      const int c   = tid + s * 256;
      const int row = c >> 2;
      const int col = (c & 3) * 8;
      unsigned short* lA = As + ((size_t)wave * 64 + s * 256) * 8;
      async_copy16(A + (size_t)(m0 + row) * K + k0 + col, lA);
    }
#pragma unroll
    for (int s = 0; s < RB; ++s) {            // B: BN*4 chunks
      const int c   = tid + s * 256;
      const int row = c >> 2;
      const int col = (c & 3) * 8;
      unsigned short* lB = Bs + ((size_t)wave * 64 + s * 256) * 8;
      async_copy16(B + (size_t)(n0 + row) * K + k0 + col, lB);
    }
    __syncthreads();

    bf16x8 af[4], bfr[TJ];
#pragma unroll
    for (int t = 0; t < 4; ++t)
      af[t]  = *reinterpret_cast<const bf16x8*>(As + (wm + t * 16 + l15) * 32 + quad * 8);
#pragma unroll
    for (int t = 0; t < TJ; ++t)
      bfr[t] = *reinterpret_cast<const bf16x8*>(Bs + (wn + t * 16 + l15) * 32 + quad * 8);
#pragma unroll
    for (int ti = 0; ti < 4; ++ti)
#pragma unroll
      for (int tj = 0; tj < TJ; ++tj)
        acc[ti][tj] = __builtin_amdgcn_mfma_f32_16x16x32_bf16(af[ti], bfr[tj], acc[ti][tj], 0, 0, 0);
  }

  // C/D layout: col = lane&15, row = quad*4 + reg (verified m89/m91)
#pragma unroll
  for (int ti = 0; ti < 4; ++ti) {
#pragma unroll
    for (int tj = 0; tj < TJ; ++tj) {
      const int mb = m0 + wm + ti * 16 + quad * 4;   // rows mb..mb+3
      const int n  = n0 + wn + tj * 16 + l15;
      if (MODE == 0) {
        const int which = n >> 10;          // 0:q 1:k 2:v
        const int n1 = n & 1023;
        const int h = n1 >> 6, d = n1 & 63;
        const int b = mb >> 11, s = mb & 2047;
        if (which == 0) {
          const size_t idx = ((size_t)(b * NH + h) * SEQ + s) * HDIM + d;
#pragma unroll
          for (int r = 0; r < 4; ++r) qo[idx + (size_t)r * HDIM] = f2bf(acc[ti][tj][r] * QSCALE);
        } else if (which == 1) {
          const size_t idx = ((size_t)(b * NH + h) * SEQ + s) * HDIM + d;
#pragma unroll
          for (int r = 0; r < 4; ++r) ko[idx + (size_t)r * HDIM] = f2bf(acc[ti][tj][r]);
        } else {
          // V^T: [b,h,d,s] — 4 consecutive s per lane -> packed 8B store
          const size_t idx = ((size_t)(b * NH + h) * HDIM + d) * SEQ + s;
          uint2 pk;
          pk.x = pk2bf(acc[ti][tj][0], acc[ti][tj][1]);
          pk.y = pk2bf(acc[ti][tj][2], acc[ti][tj][3]);
          *reinterpret_cast<uint2*>(vo + idx) = pk;
        }
      } else {
#pragma unroll
        for (int r = 0; r < 4; ++r)
          co[(size_t)(mb + r) * N + n] = acc[ti][tj][r] + bias[n];
      }
    }
  }
}

// ---------------------------------------------------------------- MFMA flash attention
// R14: Q-TILE 128 (two 64-q strips per wave) + SPLIT-K. Every Ks/Vt fragment read and
// every staged K/V byte now feeds TWO q-strips -> DS cycles and global K/V traffic per
// unit of work halve. R3's 128-tile failed pre-split-K (tail-bound, 512 variable
// blocks); with uniform <=12-iter chunks the grid is 960 blocks, fully resident.
// rel arithmetic (R3-verified): rel_sp = 8*qt + sp*4 + wave - 4*kt; subtile t is
// full if t<rel, diagonal if t==rel, skipped if t>rel.
// Fixed-origin softmax (m=0, linear partials) + register PV + fexp2. KST=72 pad.
// launch_bounds(256,4): VGPR cap 128 (~88 used) — no spill (WRITE_SIZE monitored).
#define KST 72

__global__ __launch_bounds__(256, 4) void flash_attn_mfma(
    const unsigned short* __restrict__ Qb,   // [bh][s][64], pre-scaled by log2(e)/8
    const unsigned short* __restrict__ Kb,   // [bh][s][64]
    const unsigned short* __restrict__ Vtg,  // [bh][d][2048]  (V^T)
    unsigned short* __restrict__ ctx,        // [b][s][1024] bf16
    unsigned short* __restrict__ pO,         // [768][128][64] bf16 partial O
    float* __restrict__ pL) {                // [768][128] fp32 partial l
  __shared__ __align__(16) unsigned short Ks[64 * KST];
  __shared__ __align__(16) unsigned short Vt[64 * KST];

  const int tid  = threadIdx.x;
  const int bh   = blockIdx.y;
  const int lane = tid & 63;
  const int wave = tid >> 6;
  const int l15  = lane & 15;
  const int quad = lane >> 4;

  // map blockIdx.x (0..29) -> (qt in 128-q tiles, chunk, nch)
  int qt, chunk, nch;
  {
    const int x = blockIdx.x;
    if (x < 6)       { qt = x;                chunk = 0;            nch = 1; }
    else if (x < 18) { qt = 6 + (x - 6) / 2;  chunk = (x - 6) % 2;  nch = 2; }
    else             { qt = 12 + (x - 18) / 3; chunk = (x - 18) % 3; nch = 3; }
  }
  const int q0   = qt * 128;
  const int kmax = 2 * qt + 1;          // last causal k-tile (64-key units)
  const int c0   = chunk * 12;
  const int c1   = min(kmax, c0 + 11);

  const size_t baseQK = (size_t)bh * SEQ * HDIM;
  const size_t baseV  = (size_t)bh * HDIM * SEQ;

  // staging geometry: 256 threads cover a 64x64 bf16 tile in 2 rounds of uint4
  const int srow = tid >> 3;          // 0..31
  const int scol = (tid & 7) * 8;     // 0..56

  // Q fragments (B-operand of S^T) for both strips:
  // lane holds Q[q = q0+sp*64+wave*16+l15][k = s*32+quad*8+j]
  bf16x8 qf[2][2];
#pragma unroll
  for (int sp = 0; sp < 2; ++sp) {
    const unsigned short* qp =
        Qb + baseQK + (size_t)(q0 + sp * 64 + wave * 16 + l15) * HDIM + quad * 8;
    qf[sp][0] = *reinterpret_cast<const bf16x8*>(qp);
    qf[sp][1] = *reinterpret_cast<const bf16x8*>(qp + 32);
  }

  float l_acc[2] = {0.f, 0.f};
  f32x4 o[2][4];   // o[sp][td][r] = O[q=sp*64+wave*16+quad*4+r][d=td*16+l15]
#pragma unroll
  for (int sp = 0; sp < 2; ++sp)
#pragma unroll
    for (int td = 0; td < 4; ++td) o[sp][td] = f32x4{0.f, 0.f, 0.f, 0.f};

  for (int kt = c0; kt <= c1; ++kt) {
    __syncthreads();   // everyone done reading the previous K/V tile
    {
      const uint4 k0v = *reinterpret_cast<const uint4*>(Kb + baseQK + (size_t)(kt * 64 + srow) * HDIM + scol);
      const uint4 k1v = *reinterpret_cast<const uint4*>(Kb + baseQK + (size_t)(kt * 64 + srow + 32) * HDIM + scol);
      const uint4 v0v = *reinterpret_cast<const uint4*>(Vtg + baseV + (size_t)srow * SEQ + kt * 64 + scol);
      const uint4 v1v = *reinterpret_cast<const uint4*>(Vtg + baseV + (size_t)(srow + 32) * SEQ + kt * 64 + scol);
      *reinterpret_cast<uint4*>(&Ks[srow * KST + scol]) = k0v;
      *reinterpret_cast<uint4*>(&Ks[(srow + 32) * KST + scol]) = k1v;
      *reinterpret_cast<uint4*>(&Vt[srow * KST + scol]) = v0v;
      *reinterpret_cast<uint4*>(&Vt[(srow + 32) * KST + scol]) = v1v;
    }
    __syncthreads();

    const int rel0 = 8 * qt + wave - 4 * kt;   // strip0 rel (16-key units)
    const int rel1 = rel0 + 4;                 // strip1

#pragma unroll
    for (int t = 0; t < 4; ++t) {
      if (t <= rel1) {   // strip1 needs this subtile (superset of strip0's need)
        const int krow = (t * 16 + l15) * KST;
        const bf16x8 kf0 = *reinterpret_cast<const bf16x8*>(&Ks[krow + quad * 8]);
        const bf16x8 kf1 = *reinterpret_cast<const bf16x8*>(&Ks[krow + 32 + quad * 8]);

#pragma unroll
        for (int sp = 0; sp < 2; ++sp) {
          const int rel = sp ? rel1 : rel0;
          if (t <= rel) {
            // S^T subtile: c[r] = S[key = kt*64 + t*16 + quad*4 + r][q = l15 of strip sp]
            f32x4 c = f32x4{0.f, 0.f, 0.f, 0.f};
            c = __builtin_amdgcn_mfma_f32_16x16x32_bf16(kf0, qf[sp][0], c, 0, 0, 0);
            c = __builtin_amdgcn_mfma_f32_16x16x32_bf16(kf1, qf[sp][1], c, 0, 0, 0);
            if (t == rel) {   // diagonal subtile: mask key > q
#pragma unroll
              for (int r = 0; r < 4; ++r)
                if (quad * 4 + r > l15) c[r] = -INFINITY;
            }

            // fixed-origin softmax -> A-frag in registers
            const float p0 = fexp2(c[0]);
            const float p1 = fexp2(c[1]);
            const float p2 = fexp2(c[2]);
            const float p3 = fexp2(c[3]);
            l_acc[sp] += (p0 + p1) + (p2 + p3);
            union { uint2 u; short4v s; } pf;
            pf.u.x = pk2bf(p0, p1);
            pf.u.y = pk2bf(p2, p3);

            // O += P·V (16x16x16: A m=q=l15, k=key=quad*4+j; B from V^T rows — shared)
#pragma unroll
            for (int td = 0; td < 4; ++td) {
              const short4v vf = *reinterpret_cast<const short4v*>(
                  &Vt[(td * 16 + l15) * KST + t * 16 + quad * 4]);
              o[sp][td] = mfma16(pf.s, vf, o[sp][td]);
            }
          }
        }
      }
    }
  }

  // l reduction per strip across the 4 lanes sharing l15
  float l_s[2];
#pragma unroll
  for (int sp = 0; sp < 2; ++sp) {
    float v = l_acc[sp];
    v += __shfl_xor(v, 16, 64);
    v += __shfl_xor(v, 32, 64);
    l_s[sp] = v;
  }

  if (nch == 1) {
    // single chunk: normalize and write ctx directly
    const int b = bh >> 4, h = bh & 15;
#pragma unroll
    for (int sp = 0; sp < 2; ++sp) {
      const float linv = 1.f / l_s[sp];   // for q = sp*64 + wave*16 + l15
#pragma unroll
      for (int r = 0; r < 4; ++r) {
        const float lr = __shfl(linv, quad * 4 + r, 64);
        const int sr = q0 + sp * 64 + wave * 16 + quad * 4 + r;
        const size_t ob = (size_t)(b * SEQ + sr) * DM + h * HDIM + l15;
#pragma unroll
        for (int td = 0; td < 4; ++td)
          ctx[ob + td * 16] = f2bf(o[sp][td][r] * lr);
      }
    }
  } else {
    // partial: pidx = bh*24 + pbase(qt) + chunk
    const int pb = (qt < 12) ? 2 * (qt - 6) : 12 + 3 * (qt - 12);
    const int pidx = bh * 24 + pb + chunk;
    unsigned short* po = pO + (size_t)pidx * 8192;
#pragma unroll
    for (int sp = 0; sp < 2; ++sp) {
      if (quad == 0) pL[pidx * 128 + sp * 64 + wave * 16 + l15] = l_s[sp];
#pragma unroll
      for (int r = 0; r < 4; ++r) {
        const int ql = sp * 64 + wave * 16 + quad * 4 + r;
#pragma unroll
        for (int td = 0; td < 4; ++td)
          po[ql * 64 + td * 16 + l15] = f2bf(o[sp][td][r]);
      }
    }
  }
}

// ---------------------------------------------------------------- partial combine + normalize
// grid (20, 32): pair = x>>1 selects the multi-chunk q-tile, half = x&1 selects 64 rows.
__global__ __launch_bounds__(256, 8) void attn_reduce(
    const unsigned short* __restrict__ pO, const float* __restrict__ pL,
    unsigned short* __restrict__ ctx) {
  const int x    = blockIdx.x;
  const int pair = x >> 1;
  const int half = x & 1;
  int qt, pb, nch;
  if (pair < 6) { qt = 6 + pair;          pb = 2 * pair;            nch = 2; }
  else          { qt = 12 + (pair - 6);   pb = 12 + 3 * (pair - 6); nch = 3; }
  const int bh = blockIdx.y;
  const int b = bh >> 4, h = bh & 15;
  const int pidx = bh * 24 + pb;

  const int tid = threadIdx.x;
  const int ql  = half * 64 + (tid >> 2);  // 0..127
  const int d0  = (tid & 3) * 16;          // 0,16,32,48

  float acc[16];
#pragma unroll
  for (int e = 0; e < 16; ++e) acc[e] = 0.f;
  float lsum = 0.f;

  for (int c = 0; c < nch; ++c) {
    lsum += pL[(pidx + c) * 128 + ql];
    const unsigned short* src = pO + (size_t)(pidx + c) * 8192 + ql * 64 + d0;
    const uint4 v0 = *reinterpret_cast<const uint4*>(src);
    const uint4 v1 = *reinterpret_cast<const uint4*>(src + 8);
    const unsigned short* u = reinterpret_cast<const unsigned short*>(&v0);
    const unsigned short* w = reinterpret_cast<const unsigned short*>(&v1);
#pragma unroll
    for (int e = 0; e < 8; ++e) { acc[e] += bf2f(u[e]); acc[8 + e] += bf2f(w[e]); }
  }

  const float linv = 1.f / lsum;
  unsigned int outw[8];
#pragma unroll
  for (int e = 0; e < 8; ++e)
    outw[e] = pk2bf(acc[2 * e] * linv, acc[2 * e + 1] * linv);
  unsigned short* dst = ctx + (size_t)(b * SEQ + qt * 128 + ql) * DM + h * HDIM + d0;
  *reinterpret_cast<uint4*>(dst)     = *reinterpret_cast<uint4*>(&outw[0]);
  *reinterpret_cast<uint4*>(dst + 8) = *reinterpret_cast<uint4*>(&outw[4]);
}

// ---------------------------------------------------------------- launch
extern "C" void kernel_launch(void* const* d_in, const int* in_sizes, int n_in,
                              void* d_out, int out_size, void* d_ws, size_t ws_size,
                              hipStream_t stream) {
  const float* x  = (const float*)d_in[0];
  const float* wq = (const float*)d_in[1];
  const float* wk = (const float*)d_in[2];
  const float* wv = (const float*)d_in[3];
  const float* wo = (const float*)d_in[4];
  const float* bo = (const float*)d_in[5];
  float* out = (float*)d_out;

  // ws layout (48 MB total). [0,14M) is xb+wqkvb during projections, then REUSED
  // for attention partials (pO 12 MB + pL 0.4 MB) — stream-ordered, no overlap in time.
  char* ws = (char*)d_ws;
  unsigned short* xb    = (unsigned short*)(ws);                    // [4096,1024]    8 MB
  unsigned short* wqkvb = (unsigned short*)(ws + (8ull  << 20));    // [3072,1024]    6 MB
  unsigned short* wob   = (unsigned short*)(ws + (14ull << 20));    // [1024,1024]    2 MB
  unsigned short* Qb    = (unsigned short*)(ws + (16ull << 20));    // [32,2048,64]   8 MB (pre-scaled)
  unsigned short* Kb    = (unsigned short*)(ws + (24ull << 20));    // [32,2048,64]   8 MB
  unsigned short* Vtg   = (unsigned short*)(ws + (32ull << 20));    // [32,64,2048]   8 MB (V^T)
  unsigned short* ctxb  = (unsigned short*)(ws + (40ull << 20));    // [4096,1024]    8 MB
  unsigned short* pO    = (unsigned short*)(ws);                    // [768,128,64]  12 MB
  float*          pL    = (float*)(ws + (12ull << 20) + (512ull << 10)); // [768,128] 0.4 MB

  cast_all<<<8192, 256, 0, stream>>>(x, wq, wk, wv, wo, xb, wqkvb, wob);

  dim3 g1(MTOK / 128, (3 * DM) / 128);   // 32 x 24
  gemm_bt<0><<<g1, 256, 0, stream>>>(xb, wqkvb, Qb, Kb, Vtg, nullptr, nullptr,
                                     MTOK, 3 * DM, DM);

  dim3 g2(30, NB * NH);                  // 30 chunk-blocks per bh (128-q tiles)
  flash_attn_mfma<<<g2, 256, 0, stream>>>(Qb, Kb, Vtg, ctxb, pO, pL);

  dim3 gr(20, NB * NH);                  // multi-chunk q-tiles only
  attn_reduce<<<gr, 256, 0, stream>>>(pO, pL, ctxb);

  dim3 g3(MTOK / 128, DM / 64);          // 32 x 16  (128x64 tiles -> 512 blocks)
  gemm_bt<1><<<g3, 256, 0, stream>>>(ctxb, wob, nullptr, nullptr, nullptr, out, bo,
                                     MTOK, DM, DM);
}